// Round 25
// baseline (72.864 us; speedup 1.0000x reference)
//
#include <hip/hip_runtime.h>

typedef _Float16 half4 __attribute__((ext_vector_type(4)));
typedef float f32x4 __attribute__((ext_vector_type(4)));
typedef float f32x2 __attribute__((ext_vector_type(2)));

// prep:
//  w1s=256*w1, b1s=256*b1, b2s=256*b2, b1fs=256*fc1_b (exact binade shifts)
//  wsB: conv2 B-frags fp16-split [ntile2][tap9][split2][lane64][j4]
//  wsF: fc1  B-frags fp16-split [chunk98][split2][ntile8][lane64][j4]
__global__ void prep_kernel(const float* __restrict__ w1, const float* __restrict__ b1,
                            const float* __restrict__ w2, const float* __restrict__ b2,
                            const float* __restrict__ f1w, const float* __restrict__ f1b,
                            _Float16* __restrict__ wsB, _Float16* __restrict__ wsF,
                            float* __restrict__ w1s, float* __restrict__ b1s,
                            float* __restrict__ b2s, float* __restrict__ b1fs) {
    int i = blockIdx.x * 256 + threadIdx.x;
    if (i < 144) w1s[i]  = __fmul_rn(w1[i], 256.0f);
    if (i < 16)  b1s[i]  = __fmul_rn(b1[i], 256.0f);
    if (i < 32)  b2s[i]  = __fmul_rn(b2[i], 256.0f);
    if (i < 128) b1fs[i] = __fmul_rn(f1b[i], 256.0f);
    if (i < 9216) {
        int ntile = i / 4608, r = i - ntile * 4608;
        int tap = r / 512;  int r2 = r - tap * 512;
        int split = r2 / 256; int lidx = r2 - split * 256;
        int lane = lidx >> 2, j = lidx & 3;
        int ic = ((lane >> 4) << 2) + j;
        int oc = ntile * 16 + (lane & 15);
        float w = w2[oc * 144 + ic * 9 + tap];
        _Float16 wh = (_Float16)w;
        wsB[i] = split ? (_Float16)(w - (float)wh) : wh;
    }
    if (i < 401408) {
        int c = i / 4096, rem = i - c * 4096;
        int sp = rem / 2048; int r2 = rem - sp * 2048;
        int nt = r2 / 256; int lidx = r2 - nt * 256;
        int lane = lidx >> 2, j = lidx & 3;
        int k = c * 16 + ((lane >> 4) << 2) + j;
        int o = nt * 16 + (lane & 15);
        float w = f1w[(size_t)o * 1568 + k];
        _Float16 wh = (_Float16)w;
        wsF[i] = sp ? (_Float16)(w - (float)wh) : wh;
    }
}

// conv: conv1 VALU (pk pairs; pool-then-quantize) -> conv2 K=16 MFMA, DUAL-TILE
// interleave (wave owns one nt; two mt-tiles in flight -> 4 independent MFMA
// chains + 2 A-streams) -> v-pool. Per-tile math bit-identical to R24.
#define ICGS 1168

__global__ __launch_bounds__(256, 8) void conv_kernel(
    const float* __restrict__ x,
    const float* __restrict__ w1s, const float* __restrict__ b1s,
    const _Float16* __restrict__ wsB, const float* __restrict__ b2s,
    _Float16* __restrict__ h2h)
{
    __shared__ __align__(16) union {
        float xs[900];            // conv1 input (phase 1)
        short c2h[32 * 98];       // h-pooled conv2 q-codes (phase 2; fully written)
    } u;
    __shared__ __align__(16) _Float16 h1h[4 * ICGS];  // [icg4][row16][col18][4ic]

    const int t = threadIdx.x;
    const int s = blockIdx.x;
    const int lane = t & 63;
    const int wid = t >> 6;

    // compact border zero-init (read-but-never-written entries only)
    if (t < 240) {
        int icg = t / 60, r = t - icg * 60;
        int row, col;
        if (r < 16)      { row = 0;      col = r; }
        else if (r < 32) { row = 15;     col = r - 16; }
        else if (r < 46) { row = r - 31; col = 0; }
        else             { row = r - 45; col = 15; }
        *(int2*)&h1h[icg * ICGS + (row * 18 + col) * 4] = make_int2(0, 0);
    }
    if (t < 116) {
        int idx;
        if (t < 30)      idx = t;
        else if (t < 60) idx = 29 * 30 + (t - 30);
        else if (t < 88) idx = (t - 60 + 1) * 30;
        else             idx = (t - 88 + 1) * 30 + 29;
        u.xs[idx] = 0.0f;
    }
    __syncthreads();

    const float* xin = x + (size_t)s * 784;
    for (int i = t; i < 784; i += 256) {
        int r = i / 28, c = i - r * 28;
        u.xs[(r + 1) * 30 + c + 1] = xin[i];
    }
    __syncthreads();

    // ---- conv1 (x256 weights) + pool1 + fpq + relu -> h1h fp16 q-codes ----
    {
        const int p  = (t < 196) ? t : 195;
        const int py = p / 14, px = p - 14 * (p / 14);
        const int r0 = 2 * py, c0 = 2 * px;
        float patch[16];
        #pragma unroll
        for (int i = 0; i < 4; ++i)
            #pragma unroll
            for (int j = 0; j < 4; ++j)
                patch[i * 4 + j] = u.xs[(r0 + i) * 30 + c0 + j];
        #pragma unroll 2
        for (int oc = 0; oc < 16; ++oc) {
            f32x2 a01 = {0.f, 0.f}, a23 = {0.f, 0.f};   // -> v_pk_fma_f32
            #pragma unroll
            for (int ky = 0; ky < 3; ++ky)
                #pragma unroll
                for (int kx = 0; kx < 3; ++kx) {
                    float w = w1s[oc * 9 + ky * 3 + kx];   // uniform s_load
                    f32x2 wv = {w, w};
                    f32x2 p01 = {patch[ky * 4 + kx],       patch[ky * 4 + kx + 1]};
                    f32x2 p23 = {patch[(ky + 1) * 4 + kx], patch[(ky + 1) * 4 + kx + 1]};
                    a01 = __builtin_elementwise_fma(p01, wv, a01);
                    a23 = __builtin_elementwise_fma(p23, wv, a23);
                }
            // pool-then-quantize (monotone-commute, bit-identical)
            f32x2 mm = __builtin_elementwise_max(a01, a23);
            float m = fmaxf(mm.x, mm.y);
            float q = fmaxf(rintf(__fadd_rn(m, b1s[oc])), 0.f);
            if (t < 196)
                h1h[(oc >> 2) * ICGS + ((py + 1) * 18 + (px + 1)) * 4 + (oc & 3)] = (_Float16)q;
        }
    }
    __syncthreads();   // h1h ready; xs dead -> c2h reuse

    // ---- conv2 MFMA: wave owns nt = wid>>1, parity = wid&1; dual-tile pairs ----
    const half4* __restrict__ wsB4 = (const half4*)wsB;
    {
        const int nt  = wid >> 1;        // 0..1
        const int par = wid & 1;         // 0..1
        const int nmt = par ? 6 : 7;     // tiles: mt = par + 2*j
        const float bb = b2s[nt * 16 + (lane & 15)];

        half4 bh[9], bl[9];
        #pragma unroll
        for (int tap = 0; tap < 9; ++tap) {
            bh[tap] = wsB4[(size_t)((nt * 9 + tap) * 2 + 0) * 64 + lane];
            bl[tap] = wsB4[(size_t)((nt * 9 + tap) * 2 + 1) * 64 + lane];
        }

        int j = 0;
        for (; j + 1 < nmt; j += 2) {
            const int mtA = par + 2 * j;
            const int mtB = par + 2 * (j + 1);
            int pA = mtA * 16 + (lane & 15);  pA = (pA < 196) ? pA : 195;
            int pB = mtB * 16 + (lane & 15);  pB = (pB < 196) ? pB : 195;
            const _Float16* aAb = h1h + (lane >> 4) * ICGS + ((pA / 14) * 18 + pA - 14 * (pA / 14)) * 4;
            const _Float16* aBb = h1h + (lane >> 4) * ICGS + ((pB / 14) * 18 + pB - 14 * (pB / 14)) * 4;

            f32x4 accHA = {0.f,0.f,0.f,0.f}, accLA = {0.f,0.f,0.f,0.f};
            f32x4 accHB = {0.f,0.f,0.f,0.f}, accLB = {0.f,0.f,0.f,0.f};
            __builtin_amdgcn_s_setprio(1);
            #pragma unroll
            for (int tap = 0; tap < 9; ++tap) {
                const int aoff = ((tap / 3) * 18 + (tap % 3)) * 4;
                half4 a0 = *(const half4*)(aAb + aoff);
                half4 a1 = *(const half4*)(aBb + aoff);
                accHA = __builtin_amdgcn_mfma_f32_16x16x16f16(a0, bh[tap], accHA, 0, 0, 0);
                accHB = __builtin_amdgcn_mfma_f32_16x16x16f16(a1, bh[tap], accHB, 0, 0, 0);
                accLA = __builtin_amdgcn_mfma_f32_16x16x16f16(a0, bl[tap], accLA, 0, 0, 0);
                accLB = __builtin_amdgcn_mfma_f32_16x16x16f16(a1, bl[tap], accLB, 0, 0, 0);
            }
            __builtin_amdgcn_s_setprio(0);

            const int oc = nt * 16 + (lane & 15);
            #pragma unroll
            for (int tt = 0; tt < 2; ++tt) {
                const f32x4& ah = tt ? accHB : accHA;
                const f32x4& al = tt ? accLB : accLA;
                const int pix0 = (tt ? mtB : mtA) * 16 + (lane >> 4) * 4;
                if (pix0 < 196) {
                    float x0 = __fadd_rn(ah[0], al[0]);
                    float x1 = __fadd_rn(ah[1], al[1]);
                    float x2 = __fadd_rn(ah[2], al[2]);
                    float x3 = __fadd_rn(ah[3], al[3]);
                    float h01 = fmaxf(rintf(__fadd_rn(fmaxf(x0, x1), bb)), 0.f);
                    float h23 = fmaxf(rintf(__fadd_rn(fmaxf(x2, x3), bb)), 0.f);
                    int p2 = pix0 + 2;
                    u.c2h[oc * 98 + (pix0 / 14) * 7 + ((pix0 % 14) >> 1)] = (short)(int)h01;
                    u.c2h[oc * 98 + (p2   / 14) * 7 + ((p2   % 14) >> 1)] = (short)(int)h23;
                }
            }
        }
        if (j < nmt) {                    // remainder single tile (even-parity waves)
            const int mt = par + 2 * j;
            int p = mt * 16 + (lane & 15); p = (p < 196) ? p : 195;
            const _Float16* abase = h1h + (lane >> 4) * ICGS + ((p / 14) * 18 + p - 14 * (p / 14)) * 4;
            f32x4 acch = {0.f,0.f,0.f,0.f}, accl = {0.f,0.f,0.f,0.f};
            __builtin_amdgcn_s_setprio(1);
            #pragma unroll
            for (int tap = 0; tap < 9; ++tap) {
                const int aoff = ((tap / 3) * 18 + (tap % 3)) * 4;
                half4 a = *(const half4*)(abase + aoff);
                acch = __builtin_amdgcn_mfma_f32_16x16x16f16(a, bh[tap], acch, 0, 0, 0);
                accl = __builtin_amdgcn_mfma_f32_16x16x16f16(a, bl[tap], accl, 0, 0, 0);
            }
            __builtin_amdgcn_s_setprio(0);
            const int oc = nt * 16 + (lane & 15);
            const int pix0 = mt * 16 + (lane >> 4) * 4;
            if (pix0 < 196) {
                float x0 = __fadd_rn(acch[0], accl[0]);
                float x1 = __fadd_rn(acch[1], accl[1]);
                float x2 = __fadd_rn(acch[2], accl[2]);
                float x3 = __fadd_rn(acch[3], accl[3]);
                float h01 = fmaxf(rintf(__fadd_rn(fmaxf(x0, x1), bb)), 0.f);
                float h23 = fmaxf(rintf(__fadd_rn(fmaxf(x2, x3), bb)), 0.f);
                int p2 = pix0 + 2;
                u.c2h[oc * 98 + (pix0 / 14) * 7 + ((pix0 % 14) >> 1)] = (short)(int)h01;
                u.c2h[oc * 98 + (p2   / 14) * 7 + ((p2   % 14) >> 1)] = (short)(int)h23;
            }
        }
    }
    __syncthreads();

    // ---- vertical pool -> h2h fp16 q-codes ([oc][7][7] order; exact) ----
    _Float16* h2o = h2h + (size_t)s * 1568;
    for (int i = t; i < 1568; i += 256) {
        int oc = i / 49, q = i - oc * 49;
        int qy = q / 7, qx = q - 7 * (q / 7);
        int m = max((int)u.c2h[oc * 98 + (2 * qy) * 7 + qx],
                    (int)u.c2h[oc * 98 + (2 * qy + 1) * 7 + qx]);
        h2o[i] = (_Float16)(float)m;
    }
}

// fc (K-split, R22-proven): 16 samples/block, 1024 threads = 16 waves (nt x kh).
__global__ __launch_bounds__(1024) void fc_kernel(
    const _Float16* __restrict__ h2h,
    const _Float16* __restrict__ wsF, const float* __restrict__ b1fs,
    const float* __restrict__ w2f, const float* __restrict__ b2f,
    float* __restrict__ out)
{
    __shared__ __align__(16) _Float16 Ash[16 * 394 * 4];
    __shared__ __align__(16) float Fp[8 * 64 * 4];
    __shared__ short Fsm[16 * 132];

    const int t = threadIdx.x;
    const int s0 = blockIdx.x * 16;
    const int lane = t & 63;
    const int w  = t >> 6;
    const int nt = w & 7;
    const int kh = w >> 3;

    for (int i = t; i < 3136; i += 1024) {
        int r = i / 196, c = i - r * 196;
        ((int4*)Ash)[r * 197 + c] = *(const int4*)(h2h + (size_t)(s0 + r) * 1568 + c * 8);
    }
    __syncthreads();

    const half4* __restrict__ wsF4 = (const half4*)wsF;
    const half4* __restrict__ Ash4 = (const half4*)Ash;
    f32x4 acch = {0.f, 0.f, 0.f, 0.f};
    f32x4 accl = {0.f, 0.f, 0.f, 0.f};

    const int cbeg = kh * 49;
    __builtin_amdgcn_s_setprio(1);
    for (int c = cbeg; c < cbeg + 49; ++c) {
        const int kg = c * 4 + (lane >> 4);
        half4 a = Ash4[(lane & 15) * 394 + kg];
        const size_t base = (size_t)(c * 2) * 512 + (size_t)nt * 64 + lane;
        half4 bh = wsF4[base];
        half4 bl = wsF4[base + 512];
        acch = __builtin_amdgcn_mfma_f32_16x16x16f16(a, bh, acch, 0, 0, 0);
        accl = __builtin_amdgcn_mfma_f32_16x16x16f16(a, bl, accl, 0, 0, 0);
    }
    __builtin_amdgcn_s_setprio(0);

    float acc[4];
    #pragma unroll
    for (int j = 0; j < 4; ++j) acc[j] = __fadd_rn(acch[j], accl[j]);

    if (kh == 1) {
        #pragma unroll
        for (int j = 0; j < 4; ++j) Fp[(nt * 64 + lane) * 4 + j] = acc[j];
    }
    __syncthreads();
    if (kh == 0) {
        const float bb = b1fs[nt * 16 + (lane & 15)];
        const int rbase = (lane >> 4) * 4;
        #pragma unroll
        for (int j = 0; j < 4; ++j) {
            float tot = __fadd_rn(acc[j], Fp[(nt * 64 + lane) * 4 + j]);
            float qv = fmaxf(rintf(__fadd_rn(tot, bb)), 0.f);
            Fsm[(rbase + j) * 132 + nt * 16 + (lane & 15)] = (short)(int)qv;
        }
    }
    __syncthreads();

    if (t < 160) {
        int r = t / 10, c = t - 10 * (t / 10);
        const float* wr = w2f + c * 128;
        double a2 = 0.0;
        #pragma unroll 8
        for (int k = 0; k < 128; ++k)
            a2 = fma((double)Fsm[r * 132 + k], (double)wr[k], a2);
        out[(size_t)(s0 + r) * 10 + c] = (float)(a2 * 0.00390625 + (double)b2f[c]);
    }
}

extern "C" void kernel_launch(void* const* d_in, const int* in_sizes, int n_in,
                              void* d_out, int out_size, void* d_ws, size_t ws_size,
                              hipStream_t stream) {
    const float* x   = (const float*)d_in[0];
    const float* c1w = (const float*)d_in[1];
    const float* c1b = (const float*)d_in[2];
    const float* c2w = (const float*)d_in[3];
    const float* c2b = (const float*)d_in[4];
    const float* f1w = (const float*)d_in[5];
    const float* f1b = (const float*)d_in[6];
    const float* f2w = (const float*)d_in[7];
    const float* f2b = (const float*)d_in[8];
    float* out = (float*)d_out;

    const int B = in_sizes[0] / 784;              // 4096

    _Float16* wsB = (_Float16*)d_ws;              // [9216]
    _Float16* wsF = wsB + 9216;                   // [401408]
    float* fbase  = (float*)(wsF + 401408);
    float* w1s  = fbase;                          // [144]
    float* b1s  = w1s + 144;                      // [16]
    float* b2s  = b1s + 16;                       // [32]
    float* b1fs = b2s + 32;                       // [128]
    _Float16* h2h = (_Float16*)(b1fs + 128);      // [B][1568] fp16 q-codes

    prep_kernel<<<1568, 256, 0, stream>>>(c1w, c1b, c2w, c2b, f1w, f1b,
                                          wsB, wsF, w1s, b1s, b2s, b1fs);
    conv_kernel<<<B, 256, 0, stream>>>(x, w1s, b1s, wsB, b2s, h2h);
    fc_kernel<<<B / 16, 1024, 0, stream>>>(h2h, wsF, b1fs, f2w, f2b, out);
}

// Round 26
// 68.988 us; speedup vs baseline: 1.0562x; 1.0562x over previous
//
#include <hip/hip_runtime.h>

typedef _Float16 half4 __attribute__((ext_vector_type(4)));
typedef float f32x4 __attribute__((ext_vector_type(4)));
typedef float f32x2 __attribute__((ext_vector_type(2)));

// prep:
//  w1s=256*w1, b1s=256*b1, b2s=256*b2, b1fs=256*fc1_b (exact binade shifts)
//  wsB: conv2 B-frags fp16-split [ntile2][tap9][split2][lane64][j4]
//  wsF: fc1  B-frags fp16-split [chunk98][split2][ntile8][lane64][j4]
__global__ void prep_kernel(const float* __restrict__ w1, const float* __restrict__ b1,
                            const float* __restrict__ w2, const float* __restrict__ b2,
                            const float* __restrict__ f1w, const float* __restrict__ f1b,
                            _Float16* __restrict__ wsB, _Float16* __restrict__ wsF,
                            float* __restrict__ w1s, float* __restrict__ b1s,
                            float* __restrict__ b2s, float* __restrict__ b1fs) {
    int i = blockIdx.x * 256 + threadIdx.x;
    if (i < 144) w1s[i]  = __fmul_rn(w1[i], 256.0f);
    if (i < 16)  b1s[i]  = __fmul_rn(b1[i], 256.0f);
    if (i < 32)  b2s[i]  = __fmul_rn(b2[i], 256.0f);
    if (i < 128) b1fs[i] = __fmul_rn(f1b[i], 256.0f);
    if (i < 9216) {
        int ntile = i / 4608, r = i - ntile * 4608;
        int tap = r / 512;  int r2 = r - tap * 512;
        int split = r2 / 256; int lidx = r2 - split * 256;
        int lane = lidx >> 2, j = lidx & 3;
        int ic = ((lane >> 4) << 2) + j;
        int oc = ntile * 16 + (lane & 15);
        float w = w2[oc * 144 + ic * 9 + tap];
        _Float16 wh = (_Float16)w;
        wsB[i] = split ? (_Float16)(w - (float)wh) : wh;
    }
    if (i < 401408) {
        int c = i / 4096, rem = i - c * 4096;
        int sp = rem / 2048; int r2 = rem - sp * 2048;
        int nt = r2 / 256; int lidx = r2 - nt * 256;
        int lane = lidx >> 2, j = lidx & 3;
        int k = c * 16 + ((lane >> 4) << 2) + j;
        int o = nt * 16 + (lane & 15);
        float w = f1w[(size_t)o * 1568 + k];
        _Float16 wh = (_Float16)w;
        wsF[i] = sp ? (_Float16)(w - (float)wh) : wh;
    }
}

// conv (R22/R24-proven): conv1 VALU (pk pairs; pool-then-quantize) -> conv2 K=16
// MFMA (dual split-acc, nt-major round-robin, setprio around MFMA) -> v-pool.
#define ICGS 1168

__global__ __launch_bounds__(256, 8) void conv_kernel(
    const float* __restrict__ x,
    const float* __restrict__ w1s, const float* __restrict__ b1s,
    const _Float16* __restrict__ wsB, const float* __restrict__ b2s,
    _Float16* __restrict__ h2h)
{
    __shared__ __align__(16) union {
        float xs[900];            // conv1 input (phase 1)
        short c2h[32 * 98];       // h-pooled conv2 q-codes (phase 2; fully written)
    } u;
    __shared__ __align__(16) _Float16 h1h[4 * ICGS];  // [icg4][row16][col18][4ic]

    const int t = threadIdx.x;
    const int s = blockIdx.x;
    const int lane = t & 63;
    const int wid = t >> 6;

    // compact border zero-init (read-but-never-written entries only)
    if (t < 240) {
        int icg = t / 60, r = t - icg * 60;
        int row, col;
        if (r < 16)      { row = 0;      col = r; }
        else if (r < 32) { row = 15;     col = r - 16; }
        else if (r < 46) { row = r - 31; col = 0; }
        else             { row = r - 45; col = 15; }
        *(int2*)&h1h[icg * ICGS + (row * 18 + col) * 4] = make_int2(0, 0);
    }
    if (t < 116) {
        int idx;
        if (t < 30)      idx = t;
        else if (t < 60) idx = 29 * 30 + (t - 30);
        else if (t < 88) idx = (t - 60 + 1) * 30;
        else             idx = (t - 88 + 1) * 30 + 29;
        u.xs[idx] = 0.0f;
    }
    __syncthreads();

    const float* xin = x + (size_t)s * 784;
    for (int i = t; i < 784; i += 256) {
        int r = i / 28, c = i - r * 28;
        u.xs[(r + 1) * 30 + c + 1] = xin[i];
    }
    __syncthreads();

    // ---- conv1 (x256 weights) + pool1 + fpq + relu -> h1h fp16 q-codes ----
    {
        const int p  = (t < 196) ? t : 195;
        const int py = p / 14, px = p - 14 * (p / 14);
        const int r0 = 2 * py, c0 = 2 * px;
        float patch[16];
        #pragma unroll
        for (int i = 0; i < 4; ++i)
            #pragma unroll
            for (int j = 0; j < 4; ++j)
                patch[i * 4 + j] = u.xs[(r0 + i) * 30 + c0 + j];
        #pragma unroll 2
        for (int oc = 0; oc < 16; ++oc) {
            f32x2 a01 = {0.f, 0.f}, a23 = {0.f, 0.f};   // -> v_pk_fma_f32
            #pragma unroll
            for (int ky = 0; ky < 3; ++ky)
                #pragma unroll
                for (int kx = 0; kx < 3; ++kx) {
                    float w = w1s[oc * 9 + ky * 3 + kx];   // uniform s_load
                    f32x2 wv = {w, w};
                    f32x2 p01 = {patch[ky * 4 + kx],       patch[ky * 4 + kx + 1]};
                    f32x2 p23 = {patch[(ky + 1) * 4 + kx], patch[(ky + 1) * 4 + kx + 1]};
                    a01 = __builtin_elementwise_fma(p01, wv, a01);
                    a23 = __builtin_elementwise_fma(p23, wv, a23);
                }
            // pool-then-quantize (monotone-commute, bit-identical)
            f32x2 mm = __builtin_elementwise_max(a01, a23);
            float m = fmaxf(mm.x, mm.y);
            float q = fmaxf(rintf(__fadd_rn(m, b1s[oc])), 0.f);
            if (t < 196)
                h1h[(oc >> 2) * ICGS + ((py + 1) * 18 + (px + 1)) * 4 + (oc & 3)] = (_Float16)q;
        }
    }
    __syncthreads();   // h1h ready; xs dead -> c2h reuse

    // ---- conv2 MFMA: 26 (nt,mt) tasks nt-major, round-robin over 4 waves ----
    const half4* __restrict__ wsB4 = (const half4*)wsB;
    {
        half4 bh[9], bl[9];
        int cur_nt = -1;
        for (int task = wid; task < 26; task += 4) {
            const int nt = task / 13;
            const int mt = task - nt * 13;
            if (nt != cur_nt) {            // <=2 B-frag (re)loads per wave
                cur_nt = nt;
                #pragma unroll
                for (int tap = 0; tap < 9; ++tap) {
                    bh[tap] = wsB4[(size_t)((nt * 9 + tap) * 2 + 0) * 64 + lane];
                    bl[tap] = wsB4[(size_t)((nt * 9 + tap) * 2 + 1) * 64 + lane];
                }
            }
            const float bb = b2s[nt * 16 + (lane & 15)];
            int p = mt * 16 + (lane & 15);
            p = (p < 196) ? p : 195;
            const int y = p / 14, xx = p - 14 * (p / 14);
            const _Float16* abase = h1h + (lane >> 4) * ICGS + (y * 18 + xx) * 4;

            f32x4 acch = {0.f, 0.f, 0.f, 0.f};
            f32x4 accl = {0.f, 0.f, 0.f, 0.f};
            __builtin_amdgcn_s_setprio(1);
            #pragma unroll
            for (int tap = 0; tap < 9; ++tap) {
                const int aoff = ((tap / 3) * 18 + (tap % 3)) * 4;
                half4 a = *(const half4*)(abase + aoff);
                acch = __builtin_amdgcn_mfma_f32_16x16x16f16(a, bh[tap], acch, 0, 0, 0);
                accl = __builtin_amdgcn_mfma_f32_16x16x16f16(a, bl[tap], accl, 0, 0, 0);
            }
            __builtin_amdgcn_s_setprio(0);
            const int oc = nt * 16 + (lane & 15);
            const int pix0 = mt * 16 + (lane >> 4) * 4;     // multiple of 4
            if (pix0 < 196) {
                float x0 = __fadd_rn(acch[0], accl[0]);
                float x1 = __fadd_rn(acch[1], accl[1]);
                float x2 = __fadd_rn(acch[2], accl[2]);
                float x3 = __fadd_rn(acch[3], accl[3]);
                float h01 = fmaxf(rintf(__fadd_rn(fmaxf(x0, x1), bb)), 0.f);
                float h23 = fmaxf(rintf(__fadd_rn(fmaxf(x2, x3), bb)), 0.f);
                int p2 = pix0 + 2;
                u.c2h[oc * 98 + (pix0 / 14) * 7 + ((pix0 % 14) >> 1)] = (short)(int)h01;
                u.c2h[oc * 98 + (p2   / 14) * 7 + ((p2   % 14) >> 1)] = (short)(int)h23;
            }
        }
    }
    __syncthreads();

    // ---- vertical pool -> h2h fp16 q-codes ([oc][7][7] order; exact) ----
    _Float16* h2o = h2h + (size_t)s * 1568;
    for (int i = t; i < 1568; i += 256) {
        int oc = i / 49, q = i - oc * 49;
        int qy = q / 7, qx = q - 7 * (q / 7);
        int m = max((int)u.c2h[oc * 98 + (2 * qy) * 7 + qx],
                    (int)u.c2h[oc * 98 + (2 * qy + 1) * 7 + qx]);
        h2o[i] = (_Float16)(float)m;
    }
}

// fc (K-split, R22-proven): 16 samples/block, 1024 threads = 16 waves (nt x kh).
// kh=1 deposits f32 partials in LDS; kh=0 combines ((h0+l0)+(h1+l1))+bias,
// fpq, relu -> Fsm. fc2: f64 raw pre-quant output (validated hedge).
__global__ __launch_bounds__(1024) void fc_kernel(
    const _Float16* __restrict__ h2h,
    const _Float16* __restrict__ wsF, const float* __restrict__ b1fs,
    const float* __restrict__ w2f, const float* __restrict__ b2f,
    float* __restrict__ out)
{
    __shared__ __align__(16) _Float16 Ash[16 * 394 * 4]; // [sample][kg 392+pad][4]
    __shared__ __align__(16) float Fp[8 * 64 * 4];       // kh=1 partials [nt][lane][4]
    __shared__ short Fsm[16 * 132];

    const int t = threadIdx.x;
    const int s0 = blockIdx.x * 16;
    const int lane = t & 63;
    const int w  = t >> 6;          // 0..15
    const int nt = w & 7;
    const int kh = w >> 3;

    for (int i = t; i < 3136; i += 1024) {
        int r = i / 196, c = i - r * 196;
        ((int4*)Ash)[r * 197 + c] = *(const int4*)(h2h + (size_t)(s0 + r) * 1568 + c * 8);
    }
    __syncthreads();

    const half4* __restrict__ wsF4 = (const half4*)wsF;
    const half4* __restrict__ Ash4 = (const half4*)Ash;
    f32x4 acch = {0.f, 0.f, 0.f, 0.f};
    f32x4 accl = {0.f, 0.f, 0.f, 0.f};

    const int cbeg = kh * 49;
    __builtin_amdgcn_s_setprio(1);
    for (int c = cbeg; c < cbeg + 49; ++c) {
        const int kg = c * 4 + (lane >> 4);
        half4 a = Ash4[(lane & 15) * 394 + kg];
        const size_t base = (size_t)(c * 2) * 512 + (size_t)nt * 64 + lane;
        half4 bh = wsF4[base];
        half4 bl = wsF4[base + 512];
        acch = __builtin_amdgcn_mfma_f32_16x16x16f16(a, bh, acch, 0, 0, 0);
        accl = __builtin_amdgcn_mfma_f32_16x16x16f16(a, bl, accl, 0, 0, 0);
    }
    __builtin_amdgcn_s_setprio(0);

    float acc[4];
    #pragma unroll
    for (int j = 0; j < 4; ++j) acc[j] = __fadd_rn(acch[j], accl[j]);

    if (kh == 1) {
        #pragma unroll
        for (int j = 0; j < 4; ++j) Fp[(nt * 64 + lane) * 4 + j] = acc[j];
    }
    __syncthreads();
    if (kh == 0) {
        const float bb = b1fs[nt * 16 + (lane & 15)];
        const int rbase = (lane >> 4) * 4;
        #pragma unroll
        for (int j = 0; j < 4; ++j) {
            float tot = __fadd_rn(acc[j], Fp[(nt * 64 + lane) * 4 + j]);
            float qv = fmaxf(rintf(__fadd_rn(tot, bb)), 0.f);
            Fsm[(rbase + j) * 132 + nt * 16 + (lane & 15)] = (short)(int)qv;
        }
    }
    __syncthreads();

    if (t < 160) {
        int r = t / 10, c = t - 10 * (t / 10);
        const float* wr = w2f + c * 128;
        double a2 = 0.0;
        #pragma unroll 8
        for (int k = 0; k < 128; ++k)
            a2 = fma((double)Fsm[r * 132 + k], (double)wr[k], a2);
        out[(size_t)(s0 + r) * 10 + c] = (float)(a2 * 0.00390625 + (double)b2f[c]);
    }
}

extern "C" void kernel_launch(void* const* d_in, const int* in_sizes, int n_in,
                              void* d_out, int out_size, void* d_ws, size_t ws_size,
                              hipStream_t stream) {
    const float* x   = (const float*)d_in[0];
    const float* c1w = (const float*)d_in[1];
    const float* c1b = (const float*)d_in[2];
    const float* c2w = (const float*)d_in[3];
    const float* c2b = (const float*)d_in[4];
    const float* f1w = (const float*)d_in[5];
    const float* f1b = (const float*)d_in[6];
    const float* f2w = (const float*)d_in[7];
    const float* f2b = (const float*)d_in[8];
    float* out = (float*)d_out;

    const int B = in_sizes[0] / 784;              // 4096

    _Float16* wsB = (_Float16*)d_ws;              // [9216]
    _Float16* wsF = wsB + 9216;                   // [401408]
    float* fbase  = (float*)(wsF + 401408);
    float* w1s  = fbase;                          // [144]
    float* b1s  = w1s + 144;                      // [16]
    float* b2s  = b1s + 16;                       // [32]
    float* b1fs = b2s + 32;                       // [128]
    _Float16* h2h = (_Float16*)(b1fs + 128);      // [B][1568] fp16 q-codes

    prep_kernel<<<1568, 256, 0, stream>>>(c1w, c1b, c2w, c2b, f1w, f1b,
                                          wsB, wsF, w1s, b1s, b2s, b1fs);
    conv_kernel<<<B, 256, 0, stream>>>(x, w1s, b1s, wsB, b2s, h2h);
    fc_kernel<<<B / 16, 1024, 0, stream>>>(h2h, wsF, b1fs, f2w, f2b, out);
}